// Round 5
// baseline (729.391 us; speedup 1.0000x reference)
//
#include <hip/hip_runtime.h>
#include <math.h>

// FieldFormer fused kernel, round 8 (= round 7 resubmitted; infra failure, never ran).
// vs round 6 (697us, absmax 0.0039, passing):
//  - phase-7 B-fragment prefetch: the 16 global loads for ct0/ct1 issue right
//    after the GEMM2 epilogue (before pool+LN), double-buffered B0/B1; ct2/ct3
//    reload the buffers after ct0/ct1 MFMAs issue. Round 6 exposed ~110us of
//    L2 latency by loading B inside the dependent MFMA chain post-barrier.
//  - f2bf -> v_cvt_pk_bf16_f32 inline asm (1 VALU vs 4, same RNE rounding,
//    bit-identical): 128 conversions/thread => -~380 VALU/thread.
// All other phases byte-identical to round 6.
#define KN 32
#define DD 128
#define FF 256
#define QB 2
#define MROWS (QB * KN)      // 64
#define HP 136               // pitch (ushort) for both s_hA and s_x half, 128+8

typedef __attribute__((ext_vector_type(8))) short bf16x8;
typedef __attribute__((ext_vector_type(4))) float f32x4;

__device__ __forceinline__ unsigned short f2bf(float x) {
    union { float f; unsigned u; } c; c.f = x;
    unsigned r = c.u + 0x7fffu + ((c.u >> 16) & 1u);   // RNE
    return (unsigned short)(r >> 16);
}
// HW RNE f32->bf16, 1 VALU (no builtin on gfx950; T12 verified mnemonic).
__device__ __forceinline__ unsigned short f2bf_hw(float x) {
    unsigned r;
    asm("v_cvt_pk_bf16_f32 %0, %1, %2" : "=v"(r) : "v"(x), "v"(x));
    return (unsigned short)r;
}
__device__ __forceinline__ float bf2f(unsigned short h) {
    union { unsigned u; float f; } c; c.u = ((unsigned)h) << 16;
    return c.f;
}

// gelu(x) = 0.5*x*(1+erf(x/sqrt2)), erf via A&S 7.1.26 (|err|<=1.5e-7).
__device__ __forceinline__ float gelu_f(float x) {
    float z  = __builtin_fabsf(x) * 0.70710678118654752440f;
    float z2 = z * z;
    float e  = __builtin_amdgcn_exp2f(z2 * -1.4426950408889634f);   // exp(-z^2)
    float t  = __builtin_amdgcn_rcpf(fmaf(0.3275911f, z, 1.0f));
    float p  = fmaf(1.061405429f, t, -1.453152027f);
    p = fmaf(p, t, 1.421413741f);
    p = fmaf(p, t, -0.284496736f);
    p = fmaf(p, t, 0.254829592f);
    p = p * t;
    float erfz = fmaf(-p, e, 1.0f);                 // erf(|x|/sqrt2)
    float erfs = (x < 0.0f) ? -erfz : erfz;
    float hx = 0.5f * x;
    return fmaf(hx, erfs, hx);
}

// Prep: w1 [256,128] -> bf16, w2 [128,256] -> bf16, hw1 [256,256] -> bf16.
__global__ void prep_kernel(const float* __restrict__ w1,
                            const float* __restrict__ w2,
                            const float* __restrict__ hw1,
                            unsigned short* __restrict__ w1b,
                            unsigned short* __restrict__ w2b,
                            unsigned short* __restrict__ hw1b) {
    int i = blockIdx.x * 256 + threadIdx.x;   // 0..65535
    hw1b[i] = f2bf(hw1[i]);
    if (i < 32768) {
        w1b[i] = f2bf(w1[i]);
        w2b[i] = f2bf(w2[i]);
    }
}

__launch_bounds__(256, 4)
__global__ void ff_mfma_kernel(
    const float* __restrict__ xyt_q,
    const float* __restrict__ obs_coords,
    const float* __restrict__ obs_vals,
    const int*   __restrict__ nb_idx,
    const float* __restrict__ log_gammas,
    const float* __restrict__ w_in,   // [128,4]
    const float* __restrict__ b_in,
    const float* __restrict__ ln1_g,
    const float* __restrict__ ln1_b,
    const unsigned short* __restrict__ w1b,  // [256,128] bf16
    const float* __restrict__ b1,
    const unsigned short* __restrict__ w2b,  // [128,256] bf16
    const float* __restrict__ b2,
    const float* __restrict__ hln_g,
    const float* __restrict__ hln_b,
    const unsigned short* __restrict__ hw1b, // [256,256] bf16
    const float* __restrict__ hb1,
    const float* __restrict__ hw2,
    const float* __restrict__ hb2,
    float* __restrict__ out)
{
    __shared__ __align__(16) unsigned short s_hA[MROWS * HP];  // 17408: h_ln, then h2
    __shared__ __align__(16) unsigned short s_x[MROWS * HP];   // 17408: x half-cols
    __shared__ __align__(16) float s_tokf[MROWS][4];           // 1024
    __shared__ float s_mu[QB], s_sig[QB];
    __shared__ float s_red[4][QB];

    const int t    = threadIdx.x;
    const int lane = t & 63;
    const int wv   = t >> 6;
    const int m16  = lane & 15;
    const int quad = lane >> 4;
    const int q0   = blockIdx.x * QB;

    float*          s_pool = (float*)s_x;                       // [2][256] after GEMM2
    unsigned short* s_plnb = (unsigned short*)(s_pool + 512);   // [2][256] bf16 head-LN out

    // ---- Phase 0: gather neighbors, tokens, mu/sigma (ddof=1, clip 1e-3) ----
    if (t < MROWS) {
        int qi = t >> 5, j = t & 31;
        int q = q0 + qi;
        int idx = nb_idx[q * KN + j];
        float v = obs_vals[idx];
        float g0 = expf(log_gammas[0]), g1 = expf(log_gammas[1]), g2 = expf(log_gammas[2]);
        s_tokf[t][0] = (obs_coords[idx * 3 + 0] - xyt_q[q * 3 + 0]) * g0;
        s_tokf[t][1] = (obs_coords[idx * 3 + 1] - xyt_q[q * 3 + 1]) * g1;
        s_tokf[t][2] = (obs_coords[idx * 3 + 2] - xyt_q[q * 3 + 2]) * g2;
        float s = v, ss = v * v;
        #pragma unroll
        for (int m = 1; m < 32; m <<= 1) {
            s  += __shfl_xor(s, m);
            ss += __shfl_xor(ss, m);
        }
        float mu  = s * (1.0f / KN);
        float var = (ss - (float)KN * mu * mu) * (1.0f / (KN - 1));
        float sig = fmaxf(sqrtf(fmaxf(var, 0.0f)), 1e-3f);
        if (j == 0) { s_mu[qi] = mu; s_sig[qi] = sig; }
        s_tokf[t][3] = (v - mu) / sig;
    }
    __syncthreads();

    // ---- Phase 1+2 fused: h = gelu(tok @ w_in^T + b_in), LN over 128 -> bf16 s_hA.
    {
        float4 wlo = ((const float4*)w_in)[lane];
        float4 whi = ((const float4*)w_in)[lane + 64];
        float blo = b_in[lane],  bhi = b_in[lane + 64];
        float glo = ln1_g[lane], ghi = ln1_g[lane + 64];
        float clo = ln1_b[lane], chi = ln1_b[lane + 64];
        #pragma unroll
        for (int i = 0; i < 16; i++) {
            int tok = wv * 16 + i;
            float4 tk = *(const float4*)&s_tokf[tok][0];
            float a0 = fmaf(wlo.x, tk.x, fmaf(wlo.y, tk.y, fmaf(wlo.z, tk.z, fmaf(wlo.w, tk.w, blo))));
            float a1 = fmaf(whi.x, tk.x, fmaf(whi.y, tk.y, fmaf(whi.z, tk.z, fmaf(whi.w, tk.w, bhi))));
            float v0 = gelu_f(a0), v1 = gelu_f(a1);
            float s = v0 + v1, ss = v0 * v0 + v1 * v1;
            #pragma unroll
            for (int m = 1; m < 64; m <<= 1) {
                s  += __shfl_xor(s, m);
                ss += __shfl_xor(ss, m);
            }
            float mean = s * (1.0f / DD);
            float var  = ss * (1.0f / DD) - mean * mean;
            float rstd = rsqrtf(fmaxf(var, 0.0f) + 1e-5f);
            s_hA[tok * HP + lane]      = f2bf_hw((v0 - mean) * rstd * glo + clo);
            s_hA[tok * HP + 64 + lane] = f2bf_hw((v1 - mean) * rstd * ghi + chi);
        }
    }
    __syncthreads();

    // ---- Phases 3+4 k-split: per half h, GEMM1 (x cols h*128..h*128+127) into
    //      s_x, then GEMM2 partial k-accumulate into persistent acc2.
    f32x4 acc2[4][2];
    #pragma unroll
    for (int rt = 0; rt < 4; rt++)
        #pragma unroll
        for (int ct = 0; ct < 2; ct++)
            acc2[rt][ct] = (f32x4){0.f, 0.f, 0.f, 0.f};

    #pragma unroll
    for (int h = 0; h < 2; h++) {
        // GEMM1 half: x[:, h*128 + wv*32 + ct*16 + m16] = gelu(hln @ w1^T + b1)
        {
            bf16x8 B[2][4];
            #pragma unroll
            for (int ct = 0; ct < 2; ct++)
                #pragma unroll
                for (int kk = 0; kk < 4; kk++)
                    B[ct][kk] = *(const bf16x8*)&w1b[(h * 128 + wv * 32 + ct * 16 + m16) * 128 + kk * 32 + quad * 8];
            #pragma unroll
            for (int rt = 0; rt < 4; rt++) {
                bf16x8 A[4];
                #pragma unroll
                for (int kk = 0; kk < 4; kk++)
                    A[kk] = *(const bf16x8*)&s_hA[(rt * 16 + m16) * HP + kk * 32 + quad * 8];
                #pragma unroll
                for (int ct = 0; ct < 2; ct++) {
                    f32x4 acc = {0.f, 0.f, 0.f, 0.f};
                    #pragma unroll
                    for (int kk = 0; kk < 4; kk++)
                        acc = __builtin_amdgcn_mfma_f32_16x16x32_bf16(A[kk], B[ct][kk], acc, 0, 0, 0);
                    int cl = wv * 32 + ct * 16 + m16;          // local col 0..127
                    float bb = b1[h * 128 + cl];
                    #pragma unroll
                    for (int r = 0; r < 4; r++)
                        s_x[(rt * 16 + quad * 4 + r) * HP + cl] = f2bf_hw(gelu_f(acc[r] + bb));
                }
            }
        }
        __syncthreads();
        // GEMM2 partial: acc2 += x_half @ w2[:, h*128 .. h*128+127]^T
        {
            bf16x8 B2[2][4];
            #pragma unroll
            for (int ct = 0; ct < 2; ct++)
                #pragma unroll
                for (int kk = 0; kk < 4; kk++)
                    B2[ct][kk] = *(const bf16x8*)&w2b[(wv * 32 + ct * 16 + m16) * 256 + h * 128 + kk * 32 + quad * 8];
            #pragma unroll
            for (int rt = 0; rt < 4; rt++) {
                bf16x8 A[4];
                #pragma unroll
                for (int kk = 0; kk < 4; kk++)
                    A[kk] = *(const bf16x8*)&s_x[(rt * 16 + m16) * HP + kk * 32 + quad * 8];
                #pragma unroll
                for (int ct = 0; ct < 2; ct++)
                    #pragma unroll
                    for (int kk = 0; kk < 4; kk++)
                        acc2[rt][ct] = __builtin_amdgcn_mfma_f32_16x16x32_bf16(A[kk], B2[ct][kk], acc2[rt][ct], 0, 0, 0);
            }
        }
        __syncthreads();   // h=0: before s_x overwrite; h=1: before h2/pool writes
    }

    // ---- GEMM2 epilogue: h2 = gelu(acc2 + b2) -> bf16 s_hA (s_hA reads done) ----
    #pragma unroll
    for (int rt = 0; rt < 4; rt++)
        #pragma unroll
        for (int ct = 0; ct < 2; ct++) {
            int col = wv * 32 + ct * 16 + m16;
            float bb = b2[col];
            #pragma unroll
            for (int r = 0; r < 4; r++)
                s_hA[(rt * 16 + quad * 4 + r) * HP + col] = f2bf_hw(gelu_f(acc2[rt][ct][r] + bb));
        }

    // ---- Phase-7 B prefetch (ct0, ct1): global loads only, no barrier deps.
    //      L2 latency hides under pool + head-LN. Double buffers B0/B1.
    bf16x8 B0[8], B1[8];
    #pragma unroll
    for (int kk = 0; kk < 8; kk++)
        B0[kk] = *(const bf16x8*)&hw1b[(wv * 64 + 0 * 16 + m16) * 256 + kk * 32 + quad * 8];
    #pragma unroll
    for (int kk = 0; kk < 8; kk++)
        B1[kk] = *(const bf16x8*)&hw1b[(wv * 64 + 1 * 16 + m16) * 256 + kk * 32 + quad * 8];

    __syncthreads();

    // ---- Phase 5: pool mean/max over K=32 per query (h2 in s_hA) ----
    {
        int qi = t >> 7, d = t & 127;
        float sm = 0.f, mx = -INFINITY;
        #pragma unroll
        for (int k = 0; k < KN; k++) {
            float v = bf2f(s_hA[(qi * KN + k) * HP + d]);
            sm += v; mx = fmaxf(mx, v);
        }
        s_pool[qi * 256 + d]       = sm * (1.0f / KN);
        s_pool[qi * 256 + 128 + d] = mx;
    }
    __syncthreads();

    // ---- Phase 6: head LN over 256 (one wave per query) -> bf16 s_plnb ----
    if (t < 128) {
        int qi = t >> 6, l = t & 63;
        float v0 = s_pool[qi * 256 + l],       v1 = s_pool[qi * 256 + l + 64];
        float v2 = s_pool[qi * 256 + l + 128], v3 = s_pool[qi * 256 + l + 192];
        float s = v0 + v1 + v2 + v3;
        float ss = v0 * v0 + v1 * v1 + v2 * v2 + v3 * v3;
        #pragma unroll
        for (int m = 1; m < 64; m <<= 1) {
            s  += __shfl_xor(s, m);
            ss += __shfl_xor(ss, m);
        }
        float mean = s * (1.0f / (2 * DD));
        float var  = ss * (1.0f / (2 * DD)) - mean * mean;
        float rstd = rsqrtf(fmaxf(var, 0.0f) + 1e-5f);
        s_plnb[qi * 256 + l]       = f2bf_hw((v0 - mean) * rstd * hln_g[l]       + hln_b[l]);
        s_plnb[qi * 256 + l + 64]  = f2bf_hw((v1 - mean) * rstd * hln_g[l + 64]  + hln_b[l + 64]);
        s_plnb[qi * 256 + l + 128] = f2bf_hw((v2 - mean) * rstd * hln_g[l + 128] + hln_b[l + 128]);
        s_plnb[qi * 256 + l + 192] = f2bf_hw((v3 - mean) * rstd * hln_g[l + 192] + hln_b[l + 192]);
    }
    __syncthreads();

    // ---- Phase 7: head MLP via MFMA, software-pipelined. A=[16,256] (rows 0,1 =
    //      plnb; rows 2-15 alias row 0, outputs unread). Wave wv: cols wv*64..+63.
    //      C layout: row=quad*4+r, col=m16 -> q0/q1 live in quad0, r=0/1.
    {
        const int arow = (m16 < 2) ? m16 : 0;
        bf16x8 A[8];
        #pragma unroll
        for (int kk = 0; kk < 8; kk++)
            A[kk] = *(const bf16x8*)&s_plnb[arow * 256 + kk * 32 + quad * 8];
        float c0 = 0.f, c1 = 0.f;

        // ct=0 (B0 prefetched), then reload B0 <- ct2
        f32x4 acc = {0.f, 0.f, 0.f, 0.f};
        #pragma unroll
        for (int kk = 0; kk < 8; kk++)
            acc = __builtin_amdgcn_mfma_f32_16x16x32_bf16(A[kk], B0[kk], acc, 0, 0, 0);
        #pragma unroll
        for (int kk = 0; kk < 8; kk++)
            B0[kk] = *(const bf16x8*)&hw1b[(wv * 64 + 2 * 16 + m16) * 256 + kk * 32 + quad * 8];
        if (quad == 0) {
            int col = wv * 64 + 0 * 16 + m16;
            float bb = hb1[col], w2v = hw2[col];
            c0 = fmaf(gelu_f(acc[0] + bb), w2v, c0);
            c1 = fmaf(gelu_f(acc[1] + bb), w2v, c1);
        }

        // ct=1 (B1 prefetched), then reload B1 <- ct3
        acc = (f32x4){0.f, 0.f, 0.f, 0.f};
        #pragma unroll
        for (int kk = 0; kk < 8; kk++)
            acc = __builtin_amdgcn_mfma_f32_16x16x32_bf16(A[kk], B1[kk], acc, 0, 0, 0);
        #pragma unroll
        for (int kk = 0; kk < 8; kk++)
            B1[kk] = *(const bf16x8*)&hw1b[(wv * 64 + 3 * 16 + m16) * 256 + kk * 32 + quad * 8];
        if (quad == 0) {
            int col = wv * 64 + 1 * 16 + m16;
            float bb = hb1[col], w2v = hw2[col];
            c0 = fmaf(gelu_f(acc[0] + bb), w2v, c0);
            c1 = fmaf(gelu_f(acc[1] + bb), w2v, c1);
        }

        // ct=2
        acc = (f32x4){0.f, 0.f, 0.f, 0.f};
        #pragma unroll
        for (int kk = 0; kk < 8; kk++)
            acc = __builtin_amdgcn_mfma_f32_16x16x32_bf16(A[kk], B0[kk], acc, 0, 0, 0);
        if (quad == 0) {
            int col = wv * 64 + 2 * 16 + m16;
            float bb = hb1[col], w2v = hw2[col];
            c0 = fmaf(gelu_f(acc[0] + bb), w2v, c0);
            c1 = fmaf(gelu_f(acc[1] + bb), w2v, c1);
        }

        // ct=3
        acc = (f32x4){0.f, 0.f, 0.f, 0.f};
        #pragma unroll
        for (int kk = 0; kk < 8; kk++)
            acc = __builtin_amdgcn_mfma_f32_16x16x32_bf16(A[kk], B1[kk], acc, 0, 0, 0);
        if (quad == 0) {
            int col = wv * 64 + 3 * 16 + m16;
            float bb = hb1[col], w2v = hw2[col];
            c0 = fmaf(gelu_f(acc[0] + bb), w2v, c0);
            c1 = fmaf(gelu_f(acc[1] + bb), w2v, c1);
        }

        if (quad == 0) {
            #pragma unroll
            for (int m = 1; m < 16; m <<= 1) {
                c0 += __shfl_xor(c0, m);
                c1 += __shfl_xor(c1, m);
            }
            if (m16 == 0) { s_red[wv][0] = c0; s_red[wv][1] = c1; }
        }
    }
    __syncthreads();
    if (t == 0) {
        float u0 = s_red[0][0] + s_red[1][0] + s_red[2][0] + s_red[3][0] + hb2[0];
        float u1 = s_red[0][1] + s_red[1][1] + s_red[2][1] + s_red[3][1] + hb2[0];
        out[q0 + 0] = u0 * s_sig[0] + s_mu[0];
        out[q0 + 1] = u1 * s_sig[1] + s_mu[1];
    }
}

extern "C" void kernel_launch(void* const* d_in, const int* in_sizes, int n_in,
                              void* d_out, int out_size, void* d_ws, size_t ws_size,
                              hipStream_t stream)
{
    const float* xyt_q      = (const float*)d_in[0];
    const float* obs_coords = (const float*)d_in[1];
    const float* obs_vals   = (const float*)d_in[2];
    const int*   nb_idx     = (const int*)d_in[3];
    const float* log_gammas = (const float*)d_in[4];
    const float* w_in  = (const float*)d_in[5];
    const float* b_in  = (const float*)d_in[6];
    const float* ln1_g = (const float*)d_in[7];
    const float* ln1_b = (const float*)d_in[8];
    const float* w1    = (const float*)d_in[9];
    const float* b1    = (const float*)d_in[10];
    const float* w2    = (const float*)d_in[11];
    const float* b2    = (const float*)d_in[12];
    const float* hln_g = (const float*)d_in[13];
    const float* hln_b = (const float*)d_in[14];
    const float* hw1   = (const float*)d_in[15];
    const float* hb1   = (const float*)d_in[16];
    const float* hw2   = (const float*)d_in[17];
    const float* hb2   = (const float*)d_in[18];
    float* out = (float*)d_out;

    const int Q = in_sizes[0] / 3;   // 32768

    unsigned short* w1b  = (unsigned short*)d_ws;
    unsigned short* w2b  = w1b + 32768;
    unsigned short* hw1b = (unsigned short*)((char*)d_ws + 131072);

    prep_kernel<<<256, 256, 0, stream>>>(w1, w2, hw1, w1b, w2b, hw1b);

    ff_mfma_kernel<<<Q / QB, 256, 0, stream>>>(
        xyt_q, obs_coords, obs_vals, nb_idx, log_gammas,
        w_in, b_in, ln1_g, ln1_b,
        w1b, b1, w2b, b2,
        hln_g, hln_b, hw1b, hb1, hw2, hb2, out);
}

// Round 7
// 585.598 us; speedup vs baseline: 1.2455x; 1.2455x over previous
//
#include <hip/hip_runtime.h>
#include <math.h>

// FieldFormer fused kernel, round 10.
// = round 9's head-split structure with gelu reverted to A&S 7.1.26.
// r9 post-mortem: 7.1.27's 5e-4 erf bias accumulates COHERENTLY through
// GEMM2(K=256) -> headLN (rstd amplify) -> head GEMM(K=256) => 4.15e-2 fail,
// matching the observed absmax. 7.1.26 (err 1.5e-7) is what every passing
// round used. Head-split itself is structurally proven (r6 M=16 variant
// passed bit-exact with the same fragment patterns).
//  - HEAD SPLIT: main kernel ends at pooling, writes pooled[Q][256] f32 +
//    musig[Q][2] to workspace; head_kernel (Q/64 blocks) does headLN + head
//    MLP as an M=64 MFMA GEMM. hw1 L2 traffic amortizes 32x, head VALU issue
//    collapses ~56us -> ~3us, main loses 2 barriers + latency-exposed tail.
#define KN 32
#define DD 128
#define FF 256
#define QB 2
#define MROWS (QB * KN)      // 64
#define HP 136               // pitch (ushort) for s_hA and s_x half, 128+8
#define RP 264               // head_kernel s_A pitch (ushort), 256+8

typedef __attribute__((ext_vector_type(8))) short bf16x8;
typedef __attribute__((ext_vector_type(4))) float f32x4;

__device__ __forceinline__ unsigned short f2bf(float x) {
    union { float f; unsigned u; } c; c.f = x;
    unsigned r = c.u + 0x7fffu + ((c.u >> 16) & 1u);   // RNE
    return (unsigned short)(r >> 16);
}
__device__ __forceinline__ float bf2f(unsigned short h) {
    union { unsigned u; float f; } c; c.u = ((unsigned)h) << 16;
    return c.f;
}

// gelu(x) = 0.5*x*(1+erf(x/sqrt2)), erf via A&S 7.1.26 (|err|<=1.5e-7).
__device__ __forceinline__ float gelu_f(float x) {
    float z  = __builtin_fabsf(x) * 0.70710678118654752440f;
    float z2 = z * z;
    float e  = __builtin_amdgcn_exp2f(z2 * -1.4426950408889634f);   // exp(-z^2)
    float t  = __builtin_amdgcn_rcpf(fmaf(0.3275911f, z, 1.0f));
    float p  = fmaf(1.061405429f, t, -1.453152027f);
    p = fmaf(p, t, 1.421413741f);
    p = fmaf(p, t, -0.284496736f);
    p = fmaf(p, t, 0.254829592f);
    p = p * t;
    float erfz = fmaf(-p, e, 1.0f);                 // erf(|x|/sqrt2)
    float erfs = (x < 0.0f) ? -erfz : erfz;
    float hx = 0.5f * x;
    return fmaf(hx, erfs, hx);
}

// Prep: w1 [256,128] -> bf16, w2 [128,256] -> bf16, hw1 [256,256] -> bf16.
__global__ void prep_kernel(const float* __restrict__ w1,
                            const float* __restrict__ w2,
                            const float* __restrict__ hw1,
                            unsigned short* __restrict__ w1b,
                            unsigned short* __restrict__ w2b,
                            unsigned short* __restrict__ hw1b) {
    int i = blockIdx.x * 256 + threadIdx.x;   // 0..65535
    hw1b[i] = f2bf(hw1[i]);
    if (i < 32768) {
        w1b[i] = f2bf(w1[i]);
        w2b[i] = f2bf(w2[i]);
    }
}

__launch_bounds__(256, 4)
__global__ void ff_mfma_kernel(
    const float* __restrict__ xyt_q,
    const float* __restrict__ obs_coords,
    const float* __restrict__ obs_vals,
    const int*   __restrict__ nb_idx,
    const float* __restrict__ log_gammas,
    const float* __restrict__ w_in,   // [128,4]
    const float* __restrict__ b_in,
    const float* __restrict__ ln1_g,
    const float* __restrict__ ln1_b,
    const unsigned short* __restrict__ w1b,  // [256,128] bf16
    const float* __restrict__ b1,
    const unsigned short* __restrict__ w2b,  // [128,256] bf16
    const float* __restrict__ b2,
    float* __restrict__ pooled,   // [Q][256] f32 out
    float* __restrict__ musig)    // [Q][2]   f32 out
{
    __shared__ __align__(16) unsigned short s_hA[MROWS * HP];  // 17408: h_ln, then h2
    __shared__ __align__(16) unsigned short s_x[MROWS * HP];   // 17408: x half-cols
    __shared__ __align__(16) float s_tokf[MROWS][4];           // 1024
    __shared__ float s_mu[QB], s_sig[QB];

    const int t    = threadIdx.x;
    const int lane = t & 63;
    const int wv   = t >> 6;
    const int m16  = lane & 15;
    const int quad = lane >> 4;
    const int q0   = blockIdx.x * QB;

    // ---- Phase 0: gather neighbors, tokens, mu/sigma (ddof=1, clip 1e-3) ----
    if (t < MROWS) {
        int qi = t >> 5, j = t & 31;
        int q = q0 + qi;
        int idx = nb_idx[q * KN + j];
        float v = obs_vals[idx];
        float g0 = expf(log_gammas[0]), g1 = expf(log_gammas[1]), g2 = expf(log_gammas[2]);
        s_tokf[t][0] = (obs_coords[idx * 3 + 0] - xyt_q[q * 3 + 0]) * g0;
        s_tokf[t][1] = (obs_coords[idx * 3 + 1] - xyt_q[q * 3 + 1]) * g1;
        s_tokf[t][2] = (obs_coords[idx * 3 + 2] - xyt_q[q * 3 + 2]) * g2;
        float s = v, ss = v * v;
        #pragma unroll
        for (int m = 1; m < 32; m <<= 1) {
            s  += __shfl_xor(s, m);
            ss += __shfl_xor(ss, m);
        }
        float mu  = s * (1.0f / KN);
        float var = (ss - (float)KN * mu * mu) * (1.0f / (KN - 1));
        float sig = fmaxf(sqrtf(fmaxf(var, 0.0f)), 1e-3f);
        if (j == 0) { s_mu[qi] = mu; s_sig[qi] = sig; }
        s_tokf[t][3] = (v - mu) / sig;
    }
    __syncthreads();

    // ---- Phase 1+2 fused: h = gelu(tok @ w_in^T + b_in), LN over 128 -> bf16 s_hA.
    {
        float4 wlo = ((const float4*)w_in)[lane];
        float4 whi = ((const float4*)w_in)[lane + 64];
        float blo = b_in[lane],  bhi = b_in[lane + 64];
        float glo = ln1_g[lane], ghi = ln1_g[lane + 64];
        float clo = ln1_b[lane], chi = ln1_b[lane + 64];
        #pragma unroll
        for (int i = 0; i < 16; i++) {
            int tok = wv * 16 + i;
            float4 tk = *(const float4*)&s_tokf[tok][0];
            float a0 = fmaf(wlo.x, tk.x, fmaf(wlo.y, tk.y, fmaf(wlo.z, tk.z, fmaf(wlo.w, tk.w, blo))));
            float a1 = fmaf(whi.x, tk.x, fmaf(whi.y, tk.y, fmaf(whi.z, tk.z, fmaf(whi.w, tk.w, bhi))));
            float v0 = gelu_f(a0), v1 = gelu_f(a1);
            float s = v0 + v1, ss = v0 * v0 + v1 * v1;
            #pragma unroll
            for (int m = 1; m < 64; m <<= 1) {
                s  += __shfl_xor(s, m);
                ss += __shfl_xor(ss, m);
            }
            float mean = s * (1.0f / DD);
            float var  = ss * (1.0f / DD) - mean * mean;
            float rstd = rsqrtf(fmaxf(var, 0.0f) + 1e-5f);
            s_hA[tok * HP + lane]      = f2bf((v0 - mean) * rstd * glo + clo);
            s_hA[tok * HP + 64 + lane] = f2bf((v1 - mean) * rstd * ghi + chi);
        }
    }
    __syncthreads();

    // ---- Phases 3+4 k-split: per half h, GEMM1 (x cols h*128..h*128+127) into
    //      s_x, then GEMM2 partial k-accumulate into persistent acc2.
    f32x4 acc2[4][2];
    #pragma unroll
    for (int rt = 0; rt < 4; rt++)
        #pragma unroll
        for (int ct = 0; ct < 2; ct++)
            acc2[rt][ct] = (f32x4){0.f, 0.f, 0.f, 0.f};

    #pragma unroll
    for (int h = 0; h < 2; h++) {
        // GEMM1 half: x[:, h*128 + wv*32 + ct*16 + m16] = gelu(hln @ w1^T + b1)
        {
            bf16x8 B[2][4];
            #pragma unroll
            for (int ct = 0; ct < 2; ct++)
                #pragma unroll
                for (int kk = 0; kk < 4; kk++)
                    B[ct][kk] = *(const bf16x8*)&w1b[(h * 128 + wv * 32 + ct * 16 + m16) * 128 + kk * 32 + quad * 8];
            #pragma unroll
            for (int rt = 0; rt < 4; rt++) {
                bf16x8 A[4];
                #pragma unroll
                for (int kk = 0; kk < 4; kk++)
                    A[kk] = *(const bf16x8*)&s_hA[(rt * 16 + m16) * HP + kk * 32 + quad * 8];
                #pragma unroll
                for (int ct = 0; ct < 2; ct++) {
                    f32x4 acc = {0.f, 0.f, 0.f, 0.f};
                    #pragma unroll
                    for (int kk = 0; kk < 4; kk++)
                        acc = __builtin_amdgcn_mfma_f32_16x16x32_bf16(A[kk], B[ct][kk], acc, 0, 0, 0);
                    int cl = wv * 32 + ct * 16 + m16;          // local col 0..127
                    float bb = b1[h * 128 + cl];
                    #pragma unroll
                    for (int r = 0; r < 4; r++)
                        s_x[(rt * 16 + quad * 4 + r) * HP + cl] = f2bf(gelu_f(acc[r] + bb));
                }
            }
        }
        __syncthreads();
        // GEMM2 partial: acc2 += x_half @ w2[:, h*128 .. h*128+127]^T
        {
            bf16x8 B2[2][4];
            #pragma unroll
            for (int ct = 0; ct < 2; ct++)
                #pragma unroll
                for (int kk = 0; kk < 4; kk++)
                    B2[ct][kk] = *(const bf16x8*)&w2b[(wv * 32 + ct * 16 + m16) * 256 + h * 128 + kk * 32 + quad * 8];
            #pragma unroll
            for (int rt = 0; rt < 4; rt++) {
                bf16x8 A[4];
                #pragma unroll
                for (int kk = 0; kk < 4; kk++)
                    A[kk] = *(const bf16x8*)&s_x[(rt * 16 + m16) * HP + kk * 32 + quad * 8];
                #pragma unroll
                for (int ct = 0; ct < 2; ct++)
                    #pragma unroll
                    for (int kk = 0; kk < 4; kk++)
                        acc2[rt][ct] = __builtin_amdgcn_mfma_f32_16x16x32_bf16(A[kk], B2[ct][kk], acc2[rt][ct], 0, 0, 0);
            }
        }
        __syncthreads();   // h=0: before s_x overwrite; h=1: before h2 writes
    }

    // ---- GEMM2 epilogue: h2 = gelu(acc2 + b2) -> bf16 s_hA (s_hA reads done) ----
    #pragma unroll
    for (int rt = 0; rt < 4; rt++)
        #pragma unroll
        for (int ct = 0; ct < 2; ct++) {
            int col = wv * 32 + ct * 16 + m16;
            float bb = b2[col];
            #pragma unroll
            for (int r = 0; r < 4; r++)
                s_hA[(rt * 16 + quad * 4 + r) * HP + col] = f2bf(gelu_f(acc2[rt][ct][r] + bb));
        }
    __syncthreads();

    // ---- Phase 5: pool mean/max over K=32 per query; write straight to global ----
    {
        int qi = t >> 7, d = t & 127;
        float sm = 0.f, mx = -INFINITY;
        #pragma unroll
        for (int k = 0; k < KN; k++) {
            float v = bf2f(s_hA[(qi * KN + k) * HP + d]);
            sm += v; mx = fmaxf(mx, v);
        }
        pooled[(q0 + qi) * 256 + d]       = sm * (1.0f / KN);
        pooled[(q0 + qi) * 256 + 128 + d] = mx;
    }
    if (t < QB) {
        musig[(q0 + t) * 2 + 0] = s_mu[t];
        musig[(q0 + t) * 2 + 1] = s_sig[t];
    }
}

// Head: per 64 queries, LN over 256 -> bf16 A, then hidden = gelu(A @ hw1^T + hb1),
// out = (hidden . hw2) + hb2, rescale by mu/sigma. M=64 MFMA GEMM: hw1 B-fragments
// amortize over 64 rows (vs 2 in-block before), 128 MFMA/wave.
__launch_bounds__(256, 2)
__global__ void head_kernel(
    const float* __restrict__ pooled,        // [Q][256]
    const float* __restrict__ musig,         // [Q][2]
    const unsigned short* __restrict__ hw1b, // [256][256] bf16
    const float* __restrict__ hln_g,
    const float* __restrict__ hln_b,
    const float* __restrict__ hb1,
    const float* __restrict__ hw2,
    const float* __restrict__ hb2,
    float* __restrict__ out)
{
    __shared__ __align__(16) unsigned short s_A[64 * RP];  // 33792 B
    __shared__ float s_part[4][64];

    const int t    = threadIdx.x;
    const int lane = t & 63;
    const int wv   = t >> 6;
    const int m16  = lane & 15;
    const int quad = lane >> 4;
    const int r0   = blockIdx.x * 64;

    // ---- head LN over 256 per row (wave wv: rows wv*16..+15) -> bf16 s_A ----
    {
        float g0 = hln_g[lane], g1 = hln_g[lane + 64], g2 = hln_g[lane + 128], g3 = hln_g[lane + 192];
        float c0 = hln_b[lane], c1 = hln_b[lane + 64], c2 = hln_b[lane + 128], c3 = hln_b[lane + 192];
        for (int i = 0; i < 16; i++) {
            int row = wv * 16 + i;
            const float* pr = &pooled[(r0 + row) * 256];
            float v0 = pr[lane], v1 = pr[lane + 64], v2 = pr[lane + 128], v3 = pr[lane + 192];
            float s = v0 + v1 + v2 + v3;
            float ss = v0 * v0 + v1 * v1 + v2 * v2 + v3 * v3;
            #pragma unroll
            for (int m = 1; m < 64; m <<= 1) {
                s  += __shfl_xor(s, m);
                ss += __shfl_xor(ss, m);
            }
            float mean = s * (1.0f / 256.0f);
            float var  = ss * (1.0f / 256.0f) - mean * mean;
            float rstd = rsqrtf(fmaxf(var, 0.0f) + 1e-5f);
            s_A[row * RP + lane]       = f2bf((v0 - mean) * rstd * g0 + c0);
            s_A[row * RP + lane + 64]  = f2bf((v1 - mean) * rstd * g1 + c1);
            s_A[row * RP + lane + 128] = f2bf((v2 - mean) * rstd * g2 + c2);
            s_A[row * RP + lane + 192] = f2bf((v3 - mean) * rstd * g3 + c3);
        }
    }
    __syncthreads();

    // ---- GEMM [64,256]x[256,256]^T, fused gelu*hw2 row-sum. Wave strip cols
    //      wv*64..+63; C layout row=quad*4+r, col=m16 (verified pattern). ----
    {
        float ps[4][4];
        #pragma unroll
        for (int rt = 0; rt < 4; rt++)
            #pragma unroll
            for (int r = 0; r < 4; r++)
                ps[rt][r] = 0.f;
        #pragma unroll
        for (int ct = 0; ct < 4; ct++) {
            int col = wv * 64 + ct * 16 + m16;
            bf16x8 Bf[8];
            #pragma unroll
            for (int kk = 0; kk < 8; kk++)
                Bf[kk] = *(const bf16x8*)&hw1b[col * 256 + kk * 32 + quad * 8];
            float bb = hb1[col], w2v = hw2[col];
            #pragma unroll
            for (int rt = 0; rt < 4; rt++) {
                bf16x8 A[8];
                #pragma unroll
                for (int kk = 0; kk < 8; kk++)
                    A[kk] = *(const bf16x8*)&s_A[(rt * 16 + m16) * RP + kk * 32 + quad * 8];
                f32x4 acc = {0.f, 0.f, 0.f, 0.f};
                #pragma unroll
                for (int kk = 0; kk < 8; kk++)
                    acc = __builtin_amdgcn_mfma_f32_16x16x32_bf16(A[kk], Bf[kk], acc, 0, 0, 0);
                #pragma unroll
                for (int r = 0; r < 4; r++)
                    ps[rt][r] = fmaf(gelu_f(acc[r] + bb), w2v, ps[rt][r]);
            }
        }
        // reduce partial row-sums over the 16 m16 lanes
        #pragma unroll
        for (int rt = 0; rt < 4; rt++)
            #pragma unroll
            for (int r = 0; r < 4; r++) {
                float v = ps[rt][r];
                #pragma unroll
                for (int m = 1; m < 16; m <<= 1)
                    v += __shfl_xor(v, m);
                if (m16 == 0) s_part[wv][rt * 16 + quad * 4 + r] = v;
            }
    }
    __syncthreads();
    if (t < 64) {
        float u = s_part[0][t] + s_part[1][t] + s_part[2][t] + s_part[3][t] + hb2[0];
        int q = r0 + t;
        out[q] = u * musig[q * 2 + 1] + musig[q * 2 + 0];
    }
}

extern "C" void kernel_launch(void* const* d_in, const int* in_sizes, int n_in,
                              void* d_out, int out_size, void* d_ws, size_t ws_size,
                              hipStream_t stream)
{
    const float* xyt_q      = (const float*)d_in[0];
    const float* obs_coords = (const float*)d_in[1];
    const float* obs_vals   = (const float*)d_in[2];
    const int*   nb_idx     = (const int*)d_in[3];
    const float* log_gammas = (const float*)d_in[4];
    const float* w_in  = (const float*)d_in[5];
    const float* b_in  = (const float*)d_in[6];
    const float* ln1_g = (const float*)d_in[7];
    const float* ln1_b = (const float*)d_in[8];
    const float* w1    = (const float*)d_in[9];
    const float* b1    = (const float*)d_in[10];
    const float* w2    = (const float*)d_in[11];
    const float* b2    = (const float*)d_in[12];
    const float* hln_g = (const float*)d_in[13];
    const float* hln_b = (const float*)d_in[14];
    const float* hw1   = (const float*)d_in[15];
    const float* hb1   = (const float*)d_in[16];
    const float* hw2   = (const float*)d_in[17];
    const float* hb2   = (const float*)d_in[18];
    float* out = (float*)d_out;

    const int Q = in_sizes[0] / 3;   // 32768

    // workspace layout
    unsigned short* w1b  = (unsigned short*)d_ws;                       //   0 .. 64KB
    unsigned short* w2b  = w1b + 32768;                                 //  64 .. 128KB
    unsigned short* hw1b = (unsigned short*)((char*)d_ws + 131072);     // 128 .. 256KB
    float*          musig  = (float*)((char*)d_ws + 262144);            // 256 .. 512KB
    float*          pooled = (float*)((char*)d_ws + 524288);            // 512KB .. +32MB

    prep_kernel<<<256, 256, 0, stream>>>(w1, w2, hw1, w1b, w2b, hw1b);

    ff_mfma_kernel<<<Q / QB, 256, 0, stream>>>(
        xyt_q, obs_coords, obs_vals, nb_idx, log_gammas,
        w_in, b_in, ln1_g, ln1_b,
        w1b, b1, w2b, b2,
        pooled, musig);

    head_kernel<<<Q / 64, 256, 0, stream>>>(
        pooled, musig, hw1b, hln_g, hln_b, hb1, hw2, hb2, out);
}

// Round 8
// 519.021 us; speedup vs baseline: 1.4053x; 1.1283x over previous
//
#include <hip/hip_runtime.h>
#include <math.h>

// FieldFormer fused kernel, round 11.
// vs round 10 (585us total, main 547us, absmax 0.0039, passing):
//  - QUARTER-SPLIT s_x: GEMM1 emits 64 x-cols/pass into s_x[64][72] (9216 B),
//    GEMM2 accumulates k=64/pass (global kk order 0..7 preserved -> acc2
//    BIT-IDENTICAL). s_tokf aliases s_x (dead after phase-1+2 barrier).
//    LDS 36352 -> 27136 => 4 -> 6 blocks/CU (launch_bounds (256,6)).
//    Main was VALUBusy 77% @ 44.6% occupancy: barrier stalls uncovered.
//  - POOL FUSED into GEMM2 epilogue -> global pooled[] (quad-shuffle xor16/32
//    over rows). r4's nondet failure is now explained: its fused pool wrote
//    an s_x-ALIASED s_pool with no barrier after GEMM2's s_x reads (race).
//    Global writes have no alias -> race class gone. Deletes h2 LDS store,
//    phase 5 (strided u16 reads), and 1 barrier. Mean reorder ~1e-6; max exact.
#define KN 32
#define DD 128
#define FF 256
#define QB 2
#define MROWS (QB * KN)      // 64
#define HP 136               // s_hA pitch (ushort), 128+8
#define XQP 72               // s_x quarter pitch (ushort), 64+8 (144B rows, 16B-aligned)
#define RP 264               // head_kernel s_A pitch (ushort), 256+8

typedef __attribute__((ext_vector_type(8))) short bf16x8;
typedef __attribute__((ext_vector_type(4))) float f32x4;

__device__ __forceinline__ unsigned short f2bf(float x) {
    union { float f; unsigned u; } c; c.f = x;
    unsigned r = c.u + 0x7fffu + ((c.u >> 16) & 1u);   // RNE
    return (unsigned short)(r >> 16);
}
__device__ __forceinline__ float bf2f(unsigned short h) {
    union { unsigned u; float f; } c; c.u = ((unsigned)h) << 16;
    return c.f;
}

// gelu(x) = 0.5*x*(1+erf(x/sqrt2)), erf via A&S 7.1.26 (|err|<=1.5e-7).
__device__ __forceinline__ float gelu_f(float x) {
    float z  = __builtin_fabsf(x) * 0.70710678118654752440f;
    float z2 = z * z;
    float e  = __builtin_amdgcn_exp2f(z2 * -1.4426950408889634f);   // exp(-z^2)
    float t  = __builtin_amdgcn_rcpf(fmaf(0.3275911f, z, 1.0f));
    float p  = fmaf(1.061405429f, t, -1.453152027f);
    p = fmaf(p, t, 1.421413741f);
    p = fmaf(p, t, -0.284496736f);
    p = fmaf(p, t, 0.254829592f);
    p = p * t;
    float erfz = fmaf(-p, e, 1.0f);                 // erf(|x|/sqrt2)
    float erfs = (x < 0.0f) ? -erfz : erfz;
    float hx = 0.5f * x;
    return fmaf(hx, erfs, hx);
}

// Prep: w1 [256,128] -> bf16, w2 [128,256] -> bf16, hw1 [256,256] -> bf16.
__global__ void prep_kernel(const float* __restrict__ w1,
                            const float* __restrict__ w2,
                            const float* __restrict__ hw1,
                            unsigned short* __restrict__ w1b,
                            unsigned short* __restrict__ w2b,
                            unsigned short* __restrict__ hw1b) {
    int i = blockIdx.x * 256 + threadIdx.x;   // 0..65535
    hw1b[i] = f2bf(hw1[i]);
    if (i < 32768) {
        w1b[i] = f2bf(w1[i]);
        w2b[i] = f2bf(w2[i]);
    }
}

__launch_bounds__(256, 6)
__global__ void ff_mfma_kernel(
    const float* __restrict__ xyt_q,
    const float* __restrict__ obs_coords,
    const float* __restrict__ obs_vals,
    const int*   __restrict__ nb_idx,
    const float* __restrict__ log_gammas,
    const float* __restrict__ w_in,   // [128,4]
    const float* __restrict__ b_in,
    const float* __restrict__ ln1_g,
    const float* __restrict__ ln1_b,
    const unsigned short* __restrict__ w1b,  // [256,128] bf16
    const float* __restrict__ b1,
    const unsigned short* __restrict__ w2b,  // [128,256] bf16
    const float* __restrict__ b2,
    float* __restrict__ pooled,   // [Q][256] f32 out
    float* __restrict__ musig)    // [Q][2]   f32 out
{
    __shared__ __align__(16) unsigned short s_hA[MROWS * HP];      // 17408: h_ln
    __shared__ __align__(16) unsigned char  s_xb[MROWS * XQP * 2]; // 9216: x quarter / tokf alias
    __shared__ float s_mu[QB], s_sig[QB];

    unsigned short* s_x = (unsigned short*)s_xb;
    float (*s_tokf)[4]  = (float(*)[4])s_xb;     // phase 0-1 only (dead before 1st s_x write)

    const int t    = threadIdx.x;
    const int lane = t & 63;
    const int wv   = t >> 6;
    const int m16  = lane & 15;
    const int quad = lane >> 4;
    const int q0   = blockIdx.x * QB;

    // ---- Phase 0: gather neighbors, tokens, mu/sigma (ddof=1, clip 1e-3) ----
    if (t < MROWS) {
        int qi = t >> 5, j = t & 31;
        int q = q0 + qi;
        int idx = nb_idx[q * KN + j];
        float v = obs_vals[idx];
        float g0 = expf(log_gammas[0]), g1 = expf(log_gammas[1]), g2 = expf(log_gammas[2]);
        s_tokf[t][0] = (obs_coords[idx * 3 + 0] - xyt_q[q * 3 + 0]) * g0;
        s_tokf[t][1] = (obs_coords[idx * 3 + 1] - xyt_q[q * 3 + 1]) * g1;
        s_tokf[t][2] = (obs_coords[idx * 3 + 2] - xyt_q[q * 3 + 2]) * g2;
        float s = v, ss = v * v;
        #pragma unroll
        for (int m = 1; m < 32; m <<= 1) {
            s  += __shfl_xor(s, m);
            ss += __shfl_xor(ss, m);
        }
        float mu  = s * (1.0f / KN);
        float var = (ss - (float)KN * mu * mu) * (1.0f / (KN - 1));
        float sig = fmaxf(sqrtf(fmaxf(var, 0.0f)), 1e-3f);
        if (j == 0) { s_mu[qi] = mu; s_sig[qi] = sig; }
        s_tokf[t][3] = (v - mu) / sig;
    }
    __syncthreads();

    // ---- Phase 1+2 fused: h = gelu(tok @ w_in^T + b_in), LN over 128 -> bf16 s_hA.
    {
        float4 wlo = ((const float4*)w_in)[lane];
        float4 whi = ((const float4*)w_in)[lane + 64];
        float blo = b_in[lane],  bhi = b_in[lane + 64];
        float glo = ln1_g[lane], ghi = ln1_g[lane + 64];
        float clo = ln1_b[lane], chi = ln1_b[lane + 64];
        #pragma unroll
        for (int i = 0; i < 16; i++) {
            int tok = wv * 16 + i;
            float4 tk = *(const float4*)&s_tokf[tok][0];
            float a0 = fmaf(wlo.x, tk.x, fmaf(wlo.y, tk.y, fmaf(wlo.z, tk.z, fmaf(wlo.w, tk.w, blo))));
            float a1 = fmaf(whi.x, tk.x, fmaf(whi.y, tk.y, fmaf(whi.z, tk.z, fmaf(whi.w, tk.w, bhi))));
            float v0 = gelu_f(a0), v1 = gelu_f(a1);
            float s = v0 + v1, ss = v0 * v0 + v1 * v1;
            #pragma unroll
            for (int m = 1; m < 64; m <<= 1) {
                s  += __shfl_xor(s, m);
                ss += __shfl_xor(ss, m);
            }
            float mean = s * (1.0f / DD);
            float var  = ss * (1.0f / DD) - mean * mean;
            float rstd = rsqrtf(fmaxf(var, 0.0f) + 1e-5f);
            s_hA[tok * HP + lane]      = f2bf((v0 - mean) * rstd * glo + clo);
            s_hA[tok * HP + 64 + lane] = f2bf((v1 - mean) * rstd * ghi + chi);
        }
    }
    __syncthreads();   // also retires s_tokf before s_x overwrites it

    // ---- Phases 3+4 quarter-split: per quarter qd, GEMM1 emits x cols
    //      [qd*64, qd*64+64) into s_x (wave strip = 16 cols), then GEMM2
    //      accumulates k=qd*64..+63 into persistent acc2 (global kk order
    //      0..7 preserved -> bit-identical to the half-split).
    f32x4 acc2[4][2];
    #pragma unroll
    for (int rt = 0; rt < 4; rt++)
        #pragma unroll
        for (int ct = 0; ct < 2; ct++)
            acc2[rt][ct] = (f32x4){0.f, 0.f, 0.f, 0.f};

    #pragma unroll
    for (int qd = 0; qd < 4; qd++) {
        // GEMM1 quarter: x[:, qd*64 + wv*16 + m16] = gelu(hln @ w1^T + b1)
        {
            const int gcol = qd * 64 + wv * 16 + m16;
            bf16x8 B[4];
            #pragma unroll
            for (int kk = 0; kk < 4; kk++)
                B[kk] = *(const bf16x8*)&w1b[gcol * 128 + kk * 32 + quad * 8];
            float bb = b1[gcol];
            #pragma unroll
            for (int rt = 0; rt < 4; rt++) {
                bf16x8 A[4];
                #pragma unroll
                for (int kk = 0; kk < 4; kk++)
                    A[kk] = *(const bf16x8*)&s_hA[(rt * 16 + m16) * HP + kk * 32 + quad * 8];
                f32x4 acc = {0.f, 0.f, 0.f, 0.f};
                #pragma unroll
                for (int kk = 0; kk < 4; kk++)
                    acc = __builtin_amdgcn_mfma_f32_16x16x32_bf16(A[kk], B[kk], acc, 0, 0, 0);
                #pragma unroll
                for (int r = 0; r < 4; r++)
                    s_x[(rt * 16 + quad * 4 + r) * XQP + wv * 16 + m16] = f2bf(gelu_f(acc[r] + bb));
            }
        }
        __syncthreads();
        // GEMM2 partial: acc2 += x_quarter @ w2[:, qd*64 .. qd*64+63]^T
        {
            bf16x8 B2[2][2];
            #pragma unroll
            for (int ct = 0; ct < 2; ct++)
                #pragma unroll
                for (int k2 = 0; k2 < 2; k2++)
                    B2[ct][k2] = *(const bf16x8*)&w2b[(wv * 32 + ct * 16 + m16) * 256 + qd * 64 + k2 * 32 + quad * 8];
            #pragma unroll
            for (int rt = 0; rt < 4; rt++) {
                bf16x8 A2[2];
                #pragma unroll
                for (int k2 = 0; k2 < 2; k2++)
                    A2[k2] = *(const bf16x8*)&s_x[(rt * 16 + m16) * XQP + k2 * 32 + quad * 8];
                #pragma unroll
                for (int ct = 0; ct < 2; ct++)
                    #pragma unroll
                    for (int k2 = 0; k2 < 2; k2++)
                        acc2[rt][ct] = __builtin_amdgcn_mfma_f32_16x16x32_bf16(A2[k2], B2[ct][k2], acc2[rt][ct], 0, 0, 0);
            }
        }
        if (qd < 3) __syncthreads();   // before next GEMM1 overwrites s_x
    }

    // ---- Fused GEMM2 epilogue + pool: h2 rows live in acc2 (row = rt*16+quad*4+r;
    //      rt 0,1 = query 0, rt 2,3 = query 1). gelu, then mean/max over the 8
    //      in-register rows + quad shfl_xor 16/32 -> full 32-row pool per col.
    //      Writes go straight to global pooled[] (no LDS alias -> no r4 race).
    {
        const float inv = 1.0f / KN;
        #pragma unroll
        for (int ct = 0; ct < 2; ct++) {
            int col = wv * 32 + ct * 16 + m16;
            float bb = b2[col];
            float sm0 = 0.f, mx0 = -INFINITY, sm1 = 0.f, mx1 = -INFINITY;
            #pragma unroll
            for (int r = 0; r < 4; r++) {
                float g0 = gelu_f(acc2[0][ct][r] + bb);
                float g1 = gelu_f(acc2[1][ct][r] + bb);
                float g2 = gelu_f(acc2[2][ct][r] + bb);
                float g3 = gelu_f(acc2[3][ct][r] + bb);
                sm0 += g0 + g1; mx0 = fmaxf(mx0, fmaxf(g0, g1));
                sm1 += g2 + g3; mx1 = fmaxf(mx1, fmaxf(g2, g3));
            }
            sm0 += __shfl_xor(sm0, 16); mx0 = fmaxf(mx0, __shfl_xor(mx0, 16));
            sm0 += __shfl_xor(sm0, 32); mx0 = fmaxf(mx0, __shfl_xor(mx0, 32));
            sm1 += __shfl_xor(sm1, 16); mx1 = fmaxf(mx1, __shfl_xor(mx1, 16));
            sm1 += __shfl_xor(sm1, 32); mx1 = fmaxf(mx1, __shfl_xor(mx1, 32));
            if (quad == 0) {
                pooled[(q0 + 0) * 256 + col]       = sm0 * inv;
                pooled[(q0 + 0) * 256 + 128 + col] = mx0;
                pooled[(q0 + 1) * 256 + col]       = sm1 * inv;
                pooled[(q0 + 1) * 256 + 128 + col] = mx1;
            }
        }
    }
    if (t < QB) {
        musig[(q0 + t) * 2 + 0] = s_mu[t];
        musig[(q0 + t) * 2 + 1] = s_sig[t];
    }
}

// Head: per 64 queries, LN over 256 -> bf16 A, then hidden = gelu(A @ hw1^T + hb1),
// out = (hidden . hw2) + hb2, rescale by mu/sigma. M=64 MFMA GEMM.
__launch_bounds__(256, 2)
__global__ void head_kernel(
    const float* __restrict__ pooled,        // [Q][256]
    const float* __restrict__ musig,         // [Q][2]
    const unsigned short* __restrict__ hw1b, // [256,256] bf16
    const float* __restrict__ hln_g,
    const float* __restrict__ hln_b,
    const float* __restrict__ hb1,
    const float* __restrict__ hw2,
    const float* __restrict__ hb2,
    float* __restrict__ out)
{
    __shared__ __align__(16) unsigned short s_A[64 * RP];  // 33792 B
    __shared__ float s_part[4][64];

    const int t    = threadIdx.x;
    const int lane = t & 63;
    const int wv   = t >> 6;
    const int m16  = lane & 15;
    const int quad = lane >> 4;
    const int r0   = blockIdx.x * 64;

    // ---- head LN over 256 per row (wave wv: rows wv*16..+15) -> bf16 s_A ----
    {
        float g0 = hln_g[lane], g1 = hln_g[lane + 64], g2 = hln_g[lane + 128], g3 = hln_g[lane + 192];
        float c0 = hln_b[lane], c1 = hln_b[lane + 64], c2 = hln_b[lane + 128], c3 = hln_b[lane + 192];
        for (int i = 0; i < 16; i++) {
            int row = wv * 16 + i;
            const float* pr = &pooled[(r0 + row) * 256];
            float v0 = pr[lane], v1 = pr[lane + 64], v2 = pr[lane + 128], v3 = pr[lane + 192];
            float s = v0 + v1 + v2 + v3;
            float ss = v0 * v0 + v1 * v1 + v2 * v2 + v3 * v3;
            #pragma unroll
            for (int m = 1; m < 64; m <<= 1) {
                s  += __shfl_xor(s, m);
                ss += __shfl_xor(ss, m);
            }
            float mean = s * (1.0f / 256.0f);
            float var  = ss * (1.0f / 256.0f) - mean * mean;
            float rstd = rsqrtf(fmaxf(var, 0.0f) + 1e-5f);
            s_A[row * RP + lane]       = f2bf((v0 - mean) * rstd * g0 + c0);
            s_A[row * RP + lane + 64]  = f2bf((v1 - mean) * rstd * g1 + c1);
            s_A[row * RP + lane + 128] = f2bf((v2 - mean) * rstd * g2 + c2);
            s_A[row * RP + lane + 192] = f2bf((v3 - mean) * rstd * g3 + c3);
        }
    }
    __syncthreads();

    // ---- GEMM [64,256]x[256,256]^T, fused gelu*hw2 row-sum. ----
    {
        float ps[4][4];
        #pragma unroll
        for (int rt = 0; rt < 4; rt++)
            #pragma unroll
            for (int r = 0; r < 4; r++)
                ps[rt][r] = 0.f;
        #pragma unroll
        for (int ct = 0; ct < 4; ct++) {
            int col = wv * 64 + ct * 16 + m16;
            bf16x8 Bf[8];
            #pragma unroll
            for (int kk = 0; kk < 8; kk++)
                Bf[kk] = *(const bf16x8*)&hw1b[col * 256 + kk * 32 + quad * 8];
            float bb = hb1[col], w2v = hw2[col];
            #pragma unroll
            for (int rt = 0; rt < 4; rt++) {
                bf16x8 A[8];
                #pragma unroll
                for (int kk = 0; kk < 8; kk++)
                    A[kk] = *(const bf16x8*)&s_A[(rt * 16 + m16) * RP + kk * 32 + quad * 8];
                f32x4 acc = {0.f, 0.f, 0.f, 0.f};
                #pragma unroll
                for (int kk = 0; kk < 8; kk++)
                    acc = __builtin_amdgcn_mfma_f32_16x16x32_bf16(A[kk], Bf[kk], acc, 0, 0, 0);
                #pragma unroll
                for (int r = 0; r < 4; r++)
                    ps[rt][r] = fmaf(gelu_f(acc[r] + bb), w2v, ps[rt][r]);
            }
        }
        // reduce partial row-sums over the 16 m16 lanes
        #pragma unroll
        for (int rt = 0; rt < 4; rt++)
            #pragma unroll
            for (int r = 0; r < 4; r++) {
                float v = ps[rt][r];
                #pragma unroll
                for (int m = 1; m < 16; m <<= 1)
                    v += __shfl_xor(v, m);
                if (m16 == 0) s_part[wv][rt * 16 + quad * 4 + r] = v;
            }
    }
    __syncthreads();
    if (t < 64) {
        float u = s_part[0][t] + s_part[1][t] + s_part[2][t] + s_part[3][t] + hb2[0];
        int q = r0 + t;
        out[q] = u * musig[q * 2 + 1] + musig[q * 2 + 0];
    }
}

extern "C" void kernel_launch(void* const* d_in, const int* in_sizes, int n_in,
                              void* d_out, int out_size, void* d_ws, size_t ws_size,
                              hipStream_t stream)
{
    const float* xyt_q      = (const float*)d_in[0];
    const float* obs_coords = (const float*)d_in[1];
    const float* obs_vals   = (const float*)d_in[2];
    const int*   nb_idx     = (const int*)d_in[3];
    const float* log_gammas = (const float*)d_in[4];
    const float* w_in  = (const float*)d_in[5];
    const float* b_in  = (const float*)d_in[6];
    const float* ln1_g = (const float*)d_in[7];
    const float* ln1_b = (const float*)d_in[8];
    const float* w1    = (const float*)d_in[9];
    const float* b1    = (const float*)d_in[10];
    const float* w2    = (const float*)d_in[11];
    const float* b2    = (const float*)d_in[12];
    const float* hln_g = (const float*)d_in[13];
    const float* hln_b = (const float*)d_in[14];
    const float* hw1   = (const float*)d_in[15];
    const float* hb1   = (const float*)d_in[16];
    const float* hw2   = (const float*)d_in[17];
    const float* hb2   = (const float*)d_in[18];
    float* out = (float*)d_out;

    const int Q = in_sizes[0] / 3;   // 32768

    // workspace layout
    unsigned short* w1b  = (unsigned short*)d_ws;                       //   0 .. 64KB
    unsigned short* w2b  = w1b + 32768;                                 //  64 .. 128KB
    unsigned short* hw1b = (unsigned short*)((char*)d_ws + 131072);     // 128 .. 256KB
    float*          musig  = (float*)((char*)d_ws + 262144);            // 256 .. 512KB
    float*          pooled = (float*)((char*)d_ws + 524288);            // 512KB .. +32MB

    prep_kernel<<<256, 256, 0, stream>>>(w1, w2, hw1, w1b, w2b, hw1b);

    ff_mfma_kernel<<<Q / QB, 256, 0, stream>>>(
        xyt_q, obs_coords, obs_vals, nb_idx, log_gammas,
        w_in, b_in, ln1_g, ln1_b,
        w1b, b1, w2b, b2,
        pooled, musig);

    head_kernel<<<Q / 64, 256, 0, stream>>>(
        pooled, musig, hw1b, hln_g, hln_b, hb1, hw2, hb2, out);
}